// Round 14
// baseline (302.132 us; speedup 1.0000x reference)
//
#include <hip/hip_runtime.h>
#include <math.h>

// out[b] = dot(state[b], E[idx[b]]) - logsumexp_n dot(state[b], E[n])
// B=2048, D=64, N=100000, T=1.0
//
// Round-14 = round-13 resubmitted (broker timeout, never ran).
// r12 (LDS-staged, swizzled, split-precision MFMA) + one composite lever:
// fit 4 waves/SIMD. r12 evidence: VGPR=164 -> 2 waves/SIMD (occupancy
// 10.8%), MfmaUtil 30%, ~50% idle = latency-bound; issue demand
// (MFMA 38us + LDS 16us + VALU ~8us) << 109us measured.
//  (a) single 6-deep MFMA chain per row-tile (merge cb into ca): -16 VGPR,
//      -16 adds/tile; 4 independent chains (rt=0..3) keep MFMA ILP.
//  (b) __launch_bounds__(256,4): force VGPR <=128 -> 16 waves/CU
//      (LDS 40KB x 4 blocks/CU = 160KB exact fit).
// Swizzle baked into prep_e global layout (rule #21); reads use the same
// XOR via lane-constant offsets. 125 chunks x 50 tiles = 100000 exactly.

typedef short short8 __attribute__((ext_vector_type(8)));
typedef float f32x4 __attribute__((ext_vector_type(4)));

constexpr int kD = 64;
constexpr int kChunks = 125;
constexpr int kTilesPerChunk = 50;   // 125 * 50 * 16 = 100000 exactly
constexpr int kST = 5;               // tiles per stage (20 KB)
constexpr int kStages = 10;          // 50 / 5
constexpr float kLog2e = 1.44269504088896340736f;

static __device__ inline unsigned short bf16_rne(float x) {
    unsigned int u = __builtin_bit_cast(unsigned int, x);
    u = (u + 0x7FFFu + ((u >> 16) & 1u)) >> 16;
    return (unsigned short)u;
}
static __device__ inline float bf16_f32(unsigned short h) {
    unsigned int u = ((unsigned int)h) << 16;
    return __builtin_bit_cast(float, u);
}

// S -> separate Sh/Sl arrays [B][64], scaled by log2e.
__global__ __launch_bounds__(256) void prep_s_kernel(
    const float* __restrict__ src, unsigned short* __restrict__ hi,
    unsigned short* __restrict__ lo, int total4, float scale)
{
    int i = blockIdx.x * 256 + threadIdx.x;
    if (i >= total4) return;
    float4 v = ((const float4*)src)[i];
    v.x *= scale; v.y *= scale; v.z *= scale; v.w *= scale;
    ushort4 h, l;
    h.x = bf16_rne(v.x); l.x = bf16_rne(v.x - bf16_f32(h.x));
    h.y = bf16_rne(v.y); l.y = bf16_rne(v.y - bf16_f32(h.y));
    h.z = bf16_rne(v.z); l.z = bf16_rne(v.z - bf16_f32(h.z));
    h.w = bf16_rne(v.w); l.w = bf16_rne(v.w - bf16_f32(h.w));
    ((ushort4*)hi)[i] = h;
    ((ushort4*)lo)[i] = l;
}

// E -> interleaved [tile][half(hi/lo)][item][dim] bf16, 4 KB per tile,
// with byte offset (within tile, per half) = (item*128 + dq*8) ^ ((item&7)<<4).
__global__ __launch_bounds__(256) void prep_e_kernel(
    const float* __restrict__ src, unsigned short* __restrict__ EhEl, int N)
{
    int i = blockIdx.x * 256 + threadIdx.x;       // one float4 (4 dims) each
    if (i >= N * 16) return;
    int n  = i >> 4;
    int dq = i & 15;
    float4 v = *(const float4*)(src + (size_t)n * kD + dq * 4);
    ushort4 h, l;
    h.x = bf16_rne(v.x); l.x = bf16_rne(v.x - bf16_f32(h.x));
    h.y = bf16_rne(v.y); l.y = bf16_rne(v.y - bf16_f32(h.y));
    h.z = bf16_rne(v.z); l.z = bf16_rne(v.z - bf16_f32(h.z));
    h.w = bf16_rne(v.w); l.w = bf16_rne(v.w - bf16_f32(h.w));
    int tile = n >> 4, item = n & 15;
    unsigned hb = ((unsigned)(item * 128 + dq * 8)) ^ ((unsigned)(item & 7) << 4);
    char* base = (char*)EhEl + (size_t)tile * 4096;
    *(ushort4*)(base + hb)        = h;
    *(ushort4*)(base + 2048 + hb) = l;   // +2048 is bit 11, outside XOR mask
}

#define MFMA16(a, b, c) __builtin_amdgcn_mfma_f32_16x16x32_bf16((a), (b), (c), 0, 0, 0)

__global__ __launch_bounds__(256, 4) void lse_mfma_kernel(
    const unsigned short* __restrict__ Sh,    // [B][64] bf16, scaled log2e
    const unsigned short* __restrict__ Sl,
    const unsigned short* __restrict__ EhEl,  // [6250][2][16][64] swizzled
    float* __restrict__ part,                 // [kChunks][B] exp2-sums
    int Btot)
{
    __shared__ unsigned short lds[2][kST * 2048];   // 2 x 20 KB

    const int tid  = threadIdx.x;
    const int wave = tid >> 6;
    const int lane = tid & 63;
    const int l15  = lane & 15;
    const int lhi  = lane >> 4;

    // bid = xcd + 8*rowg + 64*cgrp : all 8 rowgroups of a chunk share an XCD.
    const int bid  = blockIdx.x;
    const int xcd  = bid & 7;
    const int rowg = (bid >> 3) & 7;
    const int chunk = (bid >> 6) * 8 + xcd;
    if (chunk >= kChunks) return;                 // hole block (24 of 1024)

    const int r0 = rowg * 256 + wave * 64;        // wave's first state row

    // A fragments: [rowtile 0..3][hi/lo][kstep] -> 64 VGPRs
    short8 A[4][2][2];
    #pragma unroll
    for (int rt = 0; rt < 4; ++rt) {
        const int row = r0 + rt * 16 + l15;
        const size_t base = (size_t)row * kD + lhi * 8;
        A[rt][0][0] = *(const short8*)(Sh + base);
        A[rt][0][1] = *(const short8*)(Sh + base + 32);
        A[rt][1][0] = *(const short8*)(Sl + base);
        A[rt][1][1] = *(const short8*)(Sl + base + 32);
    }

    float acc[4][4];
    #pragma unroll
    for (int rt = 0; rt < 4; ++rt)
        #pragma unroll
        for (int j = 0; j < 4; ++j) acc[rt][j] = 0.f;

    // Swizzled lane-constant LDS read offsets (bytes within a tile half).
    const unsigned xorv = (unsigned)((l15 & 7) << 4);
    const int o_h0 = (int)(((unsigned)(l15 * 128 + lhi * 16))      ^ xorv);
    const int o_h1 = (int)(((unsigned)(l15 * 128 + lhi * 16 + 64)) ^ xorv);

    const unsigned short* src = EhEl + (size_t)chunk * kTilesPerChunk * 2048;

    // Stage s (5 tiles = 10240 elems = 20 KB) into lds[buf].
#define STAGE(buf, s) { \
    const unsigned short* sp_ = src + (size_t)(s) * (kST * 2048); \
    _Pragma("unroll") \
    for (int c = 0; c < kST; ++c) { \
        __builtin_amdgcn_global_load_lds( \
            (const __attribute__((address_space(1))) void*)(sp_ + (size_t)(c * 256 + tid) * 8), \
            (__attribute__((address_space(3))) void*)&lds[buf][(c * 256 + wave * 64) * 8], \
            16, 0, 0); \
    } }

    STAGE(0, 0);
    __syncthreads();                      // stage 0 resident

    for (int s = 0; s < kStages; ++s) {
        const int cur = s & 1;
        if (s + 1 < kStages) STAGE(cur ^ 1, s + 1);   // async prefetch

        const char* lb = (const char*)lds[cur];
        #pragma unroll
        for (int tt = 0; tt < kST; ++tt) {
            const char* tp = lb + tt * 4096;
            short8 Bh0 = *(const short8*)(tp + o_h0);
            short8 Bh1 = *(const short8*)(tp + o_h1);
            short8 Bl0 = *(const short8*)(tp + 2048 + o_h0);
            short8 Bl1 = *(const short8*)(tp + 2048 + o_h1);

            // Single 6-deep chain per row-tile; 4 independent chains (rt).
            f32x4 ca[4];
            const f32x4 z = {0.f, 0.f, 0.f, 0.f};
            #pragma unroll
            for (int rt = 0; rt < 4; ++rt) ca[rt] = MFMA16(A[rt][0][0], Bh0, z);
            #pragma unroll
            for (int rt = 0; rt < 4; ++rt) ca[rt] = MFMA16(A[rt][0][1], Bh1, ca[rt]);
            #pragma unroll
            for (int rt = 0; rt < 4; ++rt) ca[rt] = MFMA16(A[rt][1][0], Bh0, ca[rt]);
            #pragma unroll
            for (int rt = 0; rt < 4; ++rt) ca[rt] = MFMA16(A[rt][1][1], Bh1, ca[rt]);
            #pragma unroll
            for (int rt = 0; rt < 4; ++rt) ca[rt] = MFMA16(A[rt][0][0], Bl0, ca[rt]);
            #pragma unroll
            for (int rt = 0; rt < 4; ++rt) ca[rt] = MFMA16(A[rt][0][1], Bl1, ca[rt]);

            // C layout: col = lane&15, row = (lane>>4)*4 + j.
            #pragma unroll
            for (int rt = 0; rt < 4; ++rt)
                #pragma unroll
                for (int j = 0; j < 4; ++j)
                    acc[rt][j] += __builtin_amdgcn_exp2f(ca[rt][j]);
        }
        __syncthreads();   // drains vmcnt (stage s+1 ready) + readers done
    }
#undef STAGE

    // Reduce 16 column-residues (lanes sharing lhi) per row; write part.
    #pragma unroll
    for (int rt = 0; rt < 4; ++rt) {
        #pragma unroll
        for (int j = 0; j < 4; ++j) {
            float v = acc[rt][j];
            v += __shfl_xor(v, 1, 64);
            v += __shfl_xor(v, 2, 64);
            v += __shfl_xor(v, 4, 64);
            v += __shfl_xor(v, 8, 64);
            if (l15 == 0) {
                const int row = r0 + rt * 16 + lhi * 4 + j;
                part[(size_t)chunk * Btot + row] = v;
            }
        }
    }
}

__global__ __launch_bounds__(256) void finalize_kernel(
    const float* __restrict__ state,   // original fp32
    const float* __restrict__ emb,
    const int* __restrict__ idx,
    const float* __restrict__ part,    // [kChunks][B]
    float* __restrict__ out, int Btot)
{
    const int wave = threadIdx.x >> 6;
    const int lane = threadIdx.x & 63;
    const int row  = blockIdx.x * 4 + wave;

    const float* pr = part + row;
    float sv = 0.f;
    if (lane < kChunks)      sv += pr[(size_t)lane * Btot];
    if (lane + 64 < kChunks) sv += pr[(size_t)(lane + 64) * Btot];
    #pragma unroll
    for (int o = 32; o; o >>= 1) sv += __shfl_xor(sv, o, 64);
    float lse = logf(sv);

    // Selected-item logit in fp32: lane k holds dim k.
    int id = idx[row];
    float d = state[(size_t)row * kD + lane] * emb[(size_t)id * kD + lane];
    #pragma unroll
    for (int o = 32; o; o >>= 1) d += __shfl_xor(d, o, 64);

    if (lane == 0) out[row] = d - lse;
}

extern "C" void kernel_launch(void* const* d_in, const int* in_sizes, int n_in,
                              void* d_out, int out_size, void* d_ws, size_t ws_size,
                              hipStream_t stream) {
    const float* state = (const float*)d_in[0];       // [B, 64]
    const int*   idx   = (const int*)d_in[1];         // [B]
    const float* emb   = (const float*)d_in[2];       // [N, 64]
    float*       out   = (float*)d_out;               // [B]

    const int B = in_sizes[0] / kD;                   // 2048
    const int N = in_sizes[2] / kD;                   // 100000

    // Workspace layout (16B-aligned):
    char* ws = (char*)d_ws;
    size_t szE = (size_t)N * kD * 2 * sizeof(unsigned short); // 25.6 MB (hi+lo)
    size_t szS = (size_t)B * kD * sizeof(unsigned short);     // 256 KB
    unsigned short* EhEl = (unsigned short*)ws;                ws += szE;
    unsigned short* Sh   = (unsigned short*)ws;                ws += szS;
    unsigned short* Sl   = (unsigned short*)ws;                ws += szS;
    float* part = (float*)ws;                                  // 125*B*4 = 1 MB

    prep_e_kernel<<<(N * 16 + 255) / 256, 256, 0, stream>>>(emb, EhEl, N);
    int s4 = B * kD / 4;
    prep_s_kernel<<<(s4 + 255) / 256, 256, 0, stream>>>(state, Sh, Sl, s4, kLog2e);

    lse_mfma_kernel<<<1024, 256, 0, stream>>>(Sh, Sl, EhEl, part, B);

    finalize_kernel<<<B / 4, 256, 0, stream>>>(state, emb, idx, part, out, B);
}